// Round 6
// baseline (720.894 us; speedup 1.0000x reference)
//
#include <hip/hip_runtime.h>

// MI355X / gfx950. bf16 MFMA BERT attention with relu^2 "softmax".
// mfma_f32_16x16x32_bf16 layouts (HW-verified):
//   A: lane l holds A[m=l&15][k=(l>>4)*8+j]
//   B: lane l holds B[k=(l>>4)*8+j][n=l&15]
//   C/D: lane l reg r holds D[row=(l>>4)*4+r][col=l&15]
// Attention: S^T = K Q^T (C rows = keys); P round-trips through wave-private
// LDS; ctx^T = V^T P^T; K/V frags straight from global (no K/V LDS, no
// barriers in the K-loop).
// R6: key-split. 512-thread blocks, 8 waves = (4 q-chunks) x (2 key-halves).
// Per-wave AI identical to R3 (64 q/wave); wave count doubles to 4/SIMD to
// cover the serial chain latency. One-barrier LDS reduction combines the
// two key-halves at the end.

typedef __bf16 bf16x8 __attribute__((ext_vector_type(8)));
typedef __bf16 bf16x4 __attribute__((ext_vector_type(4)));
typedef float  f32x4  __attribute__((ext_vector_type(4)));
typedef float  floatx4 __attribute__((ext_vector_type(4)));

#define MFMA16(a, b, c) __builtin_amdgcn_mfma_f32_16x16x32_bf16(a, b, c, 0, 0, 0)

__device__ __forceinline__ void glds16(const __bf16* g, __bf16* l) {
    __builtin_amdgcn_global_load_lds(
        (const __attribute__((address_space(1))) void*)g,
        (__attribute__((address_space(3))) void*)l, 16, 0, 0);
}

// ---------------------------------------------------------------------------
// fp32 -> bf16 conversion: X (8M elems) then Wq/Wk/Wv (1M each).
// ---------------------------------------------------------------------------
__global__ __launch_bounds__(256) void convert_kernel(
    const float* __restrict__ X, const float* __restrict__ Wq,
    const float* __restrict__ Wk, const float* __restrict__ Wv,
    __bf16* __restrict__ Xb, __bf16* __restrict__ Wqb,
    __bf16* __restrict__ Wkb, __bf16* __restrict__ Wvb)
{
    int blk = blockIdx.x;
    const float* src; __bf16* dst; size_t base;
    if (blk < 4096)      { src = X;  dst = Xb;  base = (size_t)blk * 2048; }
    else if (blk < 4608) { src = Wq; dst = Wqb; base = (size_t)(blk - 4096) * 2048; }
    else if (blk < 5120) { src = Wk; dst = Wkb; base = (size_t)(blk - 4608) * 2048; }
    else                 { src = Wv; dst = Wvb; base = (size_t)(blk - 5120) * 2048; }
    size_t off = base + (size_t)threadIdx.x * 8;
    floatx4 a = *(const floatx4*)(src + off);
    floatx4 c = *(const floatx4*)(src + off + 4);
    bf16x8 o;
    o[0] = (__bf16)a[0]; o[1] = (__bf16)a[1]; o[2] = (__bf16)a[2]; o[3] = (__bf16)a[3];
    o[4] = (__bf16)c[0]; o[5] = (__bf16)c[1]; o[6] = (__bf16)c[2]; o[7] = (__bf16)c[3];
    *(bf16x8*)(dst + off) = o;
}

// ---------------------------------------------------------------------------
// Fused QKV GEMM: out = Xb @ Wb.T + bias. glds staging + XOR swizzle.
// blockIdx.x: 0-7 -> Q, 8-15 -> K, 16-23 -> V(transposed).
// ---------------------------------------------------------------------------
__global__ __launch_bounds__(256) void qkv_gemm_kernel(
    const __bf16* __restrict__ Xb,
    const __bf16* __restrict__ Wqb, const __bf16* __restrict__ Wkb,
    const __bf16* __restrict__ Wvb,
    const float* __restrict__ bq, const float* __restrict__ bk,
    const float* __restrict__ bv,
    __bf16* __restrict__ qws, __bf16* __restrict__ kws, __bf16* __restrict__ vws)
{
    __shared__ __bf16 As[128 * 64];
    __shared__ __bf16 Bs[128 * 64];

    const int tid  = threadIdx.x;
    const int lane = tid & 63;
    const int wave = tid >> 6;
    const int wm   = (wave >> 1) * 64;
    const int wn   = (wave & 1) * 64;
    const int quad = lane >> 4;
    const int l16  = lane & 15;
    const int m0   = blockIdx.y * 128;

    const int sel = blockIdx.x >> 3;
    const bool vmode = (sel == 2);
    const __bf16* Wb = (sel == 0) ? Wqb : (sel == 1) ? Wkb : Wvb;
    const float* bias = (sel == 0) ? bq : (sel == 1) ? bk : bv;
    __bf16* outp = (sel == 0) ? qws : (sel == 1) ? kws : vws;
    const int n0 = (blockIdx.x & 7) * 128;

    const __bf16* Pa = vmode ? As : Bs;
    const __bf16* Pb = vmode ? Bs : As;
    const int woffA = vmode ? wm : wn;
    const int woffB = vmode ? wn : wm;

    f32x4 acc[4][4] = {};

    for (int k0 = 0; k0 < 1024; k0 += 64) {
        __syncthreads();
        #pragma unroll
        for (int i = 0; i < 4; ++i) {
            int r = wave * 32 + i * 8 + (lane >> 3);
            int c = (lane & 7) ^ (r & 7);
            glds16(Xb + (size_t)(m0 + r) * 1024 + k0 + c * 8,
                   &As[(wave * 32 + i * 8) * 64]);
            glds16(Wb + (size_t)(n0 + r) * 1024 + k0 + c * 8,
                   &Bs[(wave * 32 + i * 8) * 64]);
        }
        __syncthreads();

        #pragma unroll
        for (int kk8 = 0; kk8 < 8; kk8 += 4) {
            bf16x8 af[4], bfr[4];
            #pragma unroll
            for (int a = 0; a < 4; ++a)
                af[a] = *(const bf16x8*)&Pa[(woffA + a * 16 + l16) * 64 +
                                            (((kk8 + quad) ^ (l16 & 7)) * 8)];
            #pragma unroll
            for (int bb = 0; bb < 4; ++bb)
                bfr[bb] = *(const bf16x8*)&Pb[(woffB + bb * 16 + l16) * 64 +
                                              (((kk8 + quad) ^ (l16 & 7)) * 8)];
            #pragma unroll
            for (int a = 0; a < 4; ++a)
                #pragma unroll
                for (int bb = 0; bb < 4; ++bb)
                    acc[a][bb] = MFMA16(af[a], bfr[bb], acc[a][bb]);
        }
    }

    if (!vmode) {
        #pragma unroll
        for (int a = 0; a < 4; ++a) {
            int n = n0 + woffA + a * 16 + quad * 4;
            floatx4 bv4 = *(const floatx4*)&bias[n];
            int h = n >> 6, d0 = n & 63;
            #pragma unroll
            for (int bb = 0; bb < 4; ++bb) {
                int m = m0 + woffB + bb * 16 + l16;
                int bt = m >> 11, s = m & 2047;
                bf16x4 o;
                #pragma unroll
                for (int r = 0; r < 4; ++r)
                    o[r] = (__bf16)(acc[a][bb][r] + bv4[r]);
                *(bf16x4*)&outp[((size_t)(bt * 16 + h) * 2048 + s) * 64 + d0] = o;
            }
        }
    } else {
        #pragma unroll
        for (int a = 0; a < 4; ++a) {
            int m = m0 + woffA + a * 16 + quad * 4;
            int bt = m >> 11, s0 = m & 2047;
            #pragma unroll
            for (int bb = 0; bb < 4; ++bb) {
                int n = n0 + woffB + bb * 16 + l16;
                float bvv = bias[n];
                int h = n >> 6, d = n & 63;
                bf16x4 o;
                #pragma unroll
                for (int r = 0; r < 4; ++r)
                    o[r] = (__bf16)(acc[a][bb][r] + bvv);
                *(bf16x4*)&outp[((size_t)(bt * 16 + h) * 64 + d) * 2048 + s0] = o;
            }
        }
    }
}

// ---------------------------------------------------------------------------
// Attention: grid (8, 64); block = 512 threads = 8 waves.
// wave w: qc = w&3 (64 q-rows), kh = w>>2 (key half: 1024 keys, 16 tiles).
// Per-iteration (no barriers): S^T = K Q^T -> relu^2 -> wave-private LDS P
// -> ctx^T += V^T P^T. Final: one __syncthreads, kh=1 waves dump fp32
// accumulators to LDS, kh=0 waves add and store (float4).
// ---------------------------------------------------------------------------
__global__ __launch_bounds__(512, 4) void attn_kernel(
    const __bf16* __restrict__ Q, const __bf16* __restrict__ K,
    const __bf16* __restrict__ Vt, const float* __restrict__ mask,
    float* __restrict__ out)
{
    __shared__ __bf16 Ps[8 * 64 * 72];   // 8 waves x [64 q][64 key + 8 pad]

    const int tid  = threadIdx.x;
    const int lane = tid & 63;
    const int wave = tid >> 6;
    const int qc   = wave & 3;
    const int kh   = wave >> 2;
    const int quad = lane >> 4;
    const int l16  = lane & 15;
    const int bh   = blockIdx.y;
    const int b    = bh >> 4;
    const int h    = bh & 15;
    const int q0   = blockIdx.x * 256 + qc * 64;
    const int kbase = kh * 1024;

    const __bf16* Qb = Q  + (size_t)bh * 2048 * 64;
    const __bf16* Kb = K  + (size_t)bh * 2048 * 64 + (size_t)kbase * 64;
    const __bf16* Vb = Vt + (size_t)bh * 64 * 2048 + kbase;
    const float*  mb = mask + b * 2048 + kbase;
    __bf16* Pw = &Ps[wave * 64 * 72];

    // Q fragments (B operand for S^T): lane n=l16 -> q, k = 8 contiguous d.
    bf16x8 aq[4][2];
    #pragma unroll
    for (int qi = 0; qi < 4; ++qi)
        #pragma unroll
        for (int kcd = 0; kcd < 2; ++kcd)
            aq[qi][kcd] = *(const bf16x8*)(Qb +
                (size_t)(q0 + qi * 16 + l16) * 64 + kcd * 32 + quad * 8);

    f32x4 co[4][4] = {};   // ctx^T: [d-tile][q-tile]

    for (int k0 = 0; k0 < 1024; k0 += 64) {
        // ---- S^T for 64 keys x 64 q ----
        f32x4 st[4][4] = {};
        #pragma unroll
        for (int kcd = 0; kcd < 2; ++kcd) {
            bf16x8 ak[4];
            #pragma unroll
            for (int ki = 0; ki < 4; ++ki)
                ak[ki] = *(const bf16x8*)(Kb +
                    (size_t)(k0 + ki * 16 + l16) * 64 + kcd * 32 + quad * 8);
            #pragma unroll
            for (int ki = 0; ki < 4; ++ki)
                #pragma unroll
                for (int qi = 0; qi < 4; ++qi)
                    st[ki][qi] = MFMA16(ak[ki], aq[qi][kcd], st[ki][qi]);
        }

        // ---- p = relu(s/8 + mask[key])^2 -> Pw[q][key] (b64 stores) ----
        #pragma unroll
        for (int ki = 0; ki < 4; ++ki) {
            floatx4 mk = *(const floatx4*)&mb[k0 + ki * 16 + quad * 4];
            #pragma unroll
            for (int qi = 0; qi < 4; ++qi) {
                bf16x4 pv;
                #pragma unroll
                for (int r = 0; r < 4; ++r) {
                    float x = st[ki][qi][r] * 0.125f + mk[r];
                    x = fmaxf(x, 0.0f);
                    pv[r] = (__bf16)(x * x);
                }
                *(bf16x4*)&Pw[(qi * 16 + l16) * 72 + ki * 16 + quad * 4] = pv;
            }
        }

        // ---- ctx^T += V^T P^T, contraction over 64 keys (2 chunks) ----
        #pragma unroll
        for (int kc = 0; kc < 2; ++kc) {
            bf16x8 av[4], bp[4];
            #pragma unroll
            for (int di = 0; di < 4; ++di)
                av[di] = *(const bf16x8*)(Vb +
                    (size_t)(di * 16 + l16) * 2048 + k0 + kc * 32 + quad * 8);
            #pragma unroll
            for (int qi = 0; qi < 4; ++qi)
                bp[qi] = *(const bf16x8*)&Pw[(qi * 16 + l16) * 72 +
                                             kc * 32 + quad * 8];
            #pragma unroll
            for (int di = 0; di < 4; ++di)
                #pragma unroll
                for (int qi = 0; qi < 4; ++qi)
                    co[di][qi] = MFMA16(av[di], bp[qi], co[di][qi]);
        }
    }

    // ---- combine key-halves via LDS (reuse Ps as fp32 buffer) ----
    __syncthreads();                      // all waves done with their Pw
    float* red = (float*)Ps;              // 4 regions x 4096 floats (64 KB)
    if (kh == 1) {
        #pragma unroll
        for (int di = 0; di < 4; ++di)
            #pragma unroll
            for (int qi = 0; qi < 4; ++qi)
                *(floatx4*)&red[qc * 4096 + (di * 4 + qi) * 256 + lane * 4] =
                    co[di][qi];
    }
    __syncthreads();
    if (kh == 0) {
        #pragma unroll
        for (int di = 0; di < 4; ++di) {
            int d0 = di * 16 + quad * 4;
            #pragma unroll
            for (int qi = 0; qi < 4; ++qi) {
                floatx4 other =
                    *(const floatx4*)&red[qc * 4096 + (di * 4 + qi) * 256 + lane * 4];
                f32x4 r = co[di][qi];
                r[0] += other[0]; r[1] += other[1];
                r[2] += other[2]; r[3] += other[3];
                int q = q0 + qi * 16 + l16;
                *(floatx4*)&out[(((size_t)b * 2048 + q) * 16 + h) * 64 + d0] =
                    *(floatx4*)&r;
            }
        }
    }
}

// ---------------------------------------------------------------------------
extern "C" void kernel_launch(void* const* d_in, const int* in_sizes, int n_in,
                              void* d_out, int out_size, void* d_ws, size_t ws_size,
                              hipStream_t stream) {
    const float* hidden = (const float*)d_in[0];   // [4,2048,1024]
    const float* mask   = (const float*)d_in[1];   // [4,1,1,2048]
    const float* Wq     = (const float*)d_in[2];
    const float* bq     = (const float*)d_in[3];
    const float* Wk     = (const float*)d_in[4];
    const float* bk     = (const float*)d_in[5];
    const float* Wv     = (const float*)d_in[6];
    const float* bv     = (const float*)d_in[7];
    float* out = (float*)d_out;

    __bf16* qws = (__bf16*)d_ws;                       // [64][2048][64]
    __bf16* kws = qws + (size_t)64 * 2048 * 64;        // [64][2048][64]
    __bf16* vws = kws + (size_t)64 * 2048 * 64;        // [64][64][2048]
    __bf16* Xb  = vws + (size_t)64 * 2048 * 64;        // [8192][1024]
    __bf16* Wqb = Xb  + (size_t)8192 * 1024;
    __bf16* Wkb = Wqb + (size_t)1024 * 1024;
    __bf16* Wvb = Wkb + (size_t)1024 * 1024;

    dim3 blk(256);
    convert_kernel<<<dim3(5632), blk, 0, stream>>>(hidden, Wq, Wk, Wv,
                                                   Xb, Wqb, Wkb, Wvb);
    qkv_gemm_kernel<<<dim3(24, 64), blk, 0, stream>>>(Xb, Wqb, Wkb, Wvb,
                                                      bq, bk, bv, qws, kws, vws);
    attn_kernel<<<dim3(8, 64), dim3(512), 0, stream>>>(qws, kws, vws, mask, out);
}

// Round 7
// 274.936 us; speedup vs baseline: 2.6220x; 2.6220x over previous
//
#include <hip/hip_runtime.h>

// MI355X / gfx950. bf16 MFMA BERT attention with relu^2 "softmax".
// mfma_f32_16x16x32_bf16 layouts (HW-verified):
//   A: lane l holds A[m=l&15][k=(l>>4)*8+j]
//   B: lane l holds B[k=(l>>4)*8+j][n=l&15]
//   C/D: lane l reg r holds D[row=(l>>4)*4+r][col=l&15]
// mfma_f32_16x16x16_bf16 (K=16):
//   A: lane l holds A[m=l&15][k=(l>>4)*4+j]  <-- matches 16x16x32 C-layout
//   B: lane l holds B[k=(l>>4)*4+j][n=l&15]
// R7 attention: S^T = K Q^T (C rows = keys). relu^2(S^T) is ALREADY the
// A-operand of a 16x16x16 PV MFMA (P[q=l16][key=quad*4+r]) -> P never
// leaves registers. K/V staged per-block via double-buffered glds LDS.

typedef __bf16 bf16x8 __attribute__((ext_vector_type(8)));
typedef __bf16 bf16x4 __attribute__((ext_vector_type(4)));
typedef short  s16x4  __attribute__((ext_vector_type(4)));
typedef float  f32x4  __attribute__((ext_vector_type(4)));
typedef float  floatx4 __attribute__((ext_vector_type(4)));

#define MFMA16(a, b, c) __builtin_amdgcn_mfma_f32_16x16x32_bf16(a, b, c, 0, 0, 0)
// K=16 bf16 MFMA (gfx90a+ builtin, instruction present on gfx950 per ISA)
#define MFMA16K16(a, b, c) \
    __builtin_amdgcn_mfma_f32_16x16x16bf16_1k(a, b, c, 0, 0, 0)

#define WAITCNT_VM4() __builtin_amdgcn_s_waitcnt(0x0F74)   // vmcnt(4)

__device__ __forceinline__ void glds16(const __bf16* g, __bf16* l) {
    __builtin_amdgcn_global_load_lds(
        (const __attribute__((address_space(1))) void*)g,
        (__attribute__((address_space(3))) void*)l, 16, 0, 0);
}

// ---------------------------------------------------------------------------
// fp32 -> bf16 conversion: X (8M elems) then Wq/Wk/Wv (1M each).
// ---------------------------------------------------------------------------
__global__ __launch_bounds__(256) void convert_kernel(
    const float* __restrict__ X, const float* __restrict__ Wq,
    const float* __restrict__ Wk, const float* __restrict__ Wv,
    __bf16* __restrict__ Xb, __bf16* __restrict__ Wqb,
    __bf16* __restrict__ Wkb, __bf16* __restrict__ Wvb)
{
    int blk = blockIdx.x;
    const float* src; __bf16* dst; size_t base;
    if (blk < 4096)      { src = X;  dst = Xb;  base = (size_t)blk * 2048; }
    else if (blk < 4608) { src = Wq; dst = Wqb; base = (size_t)(blk - 4096) * 2048; }
    else if (blk < 5120) { src = Wk; dst = Wkb; base = (size_t)(blk - 4608) * 2048; }
    else                 { src = Wv; dst = Wvb; base = (size_t)(blk - 5120) * 2048; }
    size_t off = base + (size_t)threadIdx.x * 8;
    floatx4 a = *(const floatx4*)(src + off);
    floatx4 c = *(const floatx4*)(src + off + 4);
    bf16x8 o;
    o[0] = (__bf16)a[0]; o[1] = (__bf16)a[1]; o[2] = (__bf16)a[2]; o[3] = (__bf16)a[3];
    o[4] = (__bf16)c[0]; o[5] = (__bf16)c[1]; o[6] = (__bf16)c[2]; o[7] = (__bf16)c[3];
    *(bf16x8*)(dst + off) = o;
}

// ---------------------------------------------------------------------------
// Fused QKV GEMM: out = Xb @ Wb.T + bias. glds staging + XOR swizzle.
// blockIdx.x: 0-7 -> Q, 8-15 -> K, 16-23 -> V(transposed).
// ---------------------------------------------------------------------------
__global__ __launch_bounds__(256) void qkv_gemm_kernel(
    const __bf16* __restrict__ Xb,
    const __bf16* __restrict__ Wqb, const __bf16* __restrict__ Wkb,
    const __bf16* __restrict__ Wvb,
    const float* __restrict__ bq, const float* __restrict__ bk,
    const float* __restrict__ bv,
    __bf16* __restrict__ qws, __bf16* __restrict__ kws, __bf16* __restrict__ vws)
{
    __shared__ __bf16 As[128 * 64];
    __shared__ __bf16 Bs[128 * 64];

    const int tid  = threadIdx.x;
    const int lane = tid & 63;
    const int wave = tid >> 6;
    const int wm   = (wave >> 1) * 64;
    const int wn   = (wave & 1) * 64;
    const int quad = lane >> 4;
    const int l16  = lane & 15;
    const int m0   = blockIdx.y * 128;

    const int sel = blockIdx.x >> 3;
    const bool vmode = (sel == 2);
    const __bf16* Wb = (sel == 0) ? Wqb : (sel == 1) ? Wkb : Wvb;
    const float* bias = (sel == 0) ? bq : (sel == 1) ? bk : bv;
    __bf16* outp = (sel == 0) ? qws : (sel == 1) ? kws : vws;
    const int n0 = (blockIdx.x & 7) * 128;

    const __bf16* Pa = vmode ? As : Bs;
    const __bf16* Pb = vmode ? Bs : As;
    const int woffA = vmode ? wm : wn;
    const int woffB = vmode ? wn : wm;

    f32x4 acc[4][4] = {};

    for (int k0 = 0; k0 < 1024; k0 += 64) {
        __syncthreads();
        #pragma unroll
        for (int i = 0; i < 4; ++i) {
            int r = wave * 32 + i * 8 + (lane >> 3);
            int c = (lane & 7) ^ (r & 7);
            glds16(Xb + (size_t)(m0 + r) * 1024 + k0 + c * 8,
                   &As[(wave * 32 + i * 8) * 64]);
            glds16(Wb + (size_t)(n0 + r) * 1024 + k0 + c * 8,
                   &Bs[(wave * 32 + i * 8) * 64]);
        }
        __syncthreads();

        #pragma unroll
        for (int kk8 = 0; kk8 < 8; kk8 += 4) {
            bf16x8 af[4], bfr[4];
            #pragma unroll
            for (int a = 0; a < 4; ++a)
                af[a] = *(const bf16x8*)&Pa[(woffA + a * 16 + l16) * 64 +
                                            (((kk8 + quad) ^ (l16 & 7)) * 8)];
            #pragma unroll
            for (int bb = 0; bb < 4; ++bb)
                bfr[bb] = *(const bf16x8*)&Pb[(woffB + bb * 16 + l16) * 64 +
                                              (((kk8 + quad) ^ (l16 & 7)) * 8)];
            #pragma unroll
            for (int a = 0; a < 4; ++a)
                #pragma unroll
                for (int bb = 0; bb < 4; ++bb)
                    acc[a][bb] = MFMA16(af[a], bfr[bb], acc[a][bb]);
        }
    }

    if (!vmode) {
        #pragma unroll
        for (int a = 0; a < 4; ++a) {
            int n = n0 + woffA + a * 16 + quad * 4;
            floatx4 bv4 = *(const floatx4*)&bias[n];
            int h = n >> 6, d0 = n & 63;
            #pragma unroll
            for (int bb = 0; bb < 4; ++bb) {
                int m = m0 + woffB + bb * 16 + l16;
                int bt = m >> 11, s = m & 2047;
                bf16x4 o;
                #pragma unroll
                for (int r = 0; r < 4; ++r)
                    o[r] = (__bf16)(acc[a][bb][r] + bv4[r]);
                *(bf16x4*)&outp[((size_t)(bt * 16 + h) * 2048 + s) * 64 + d0] = o;
            }
        }
    } else {
        #pragma unroll
        for (int a = 0; a < 4; ++a) {
            int m = m0 + woffA + a * 16 + quad * 4;
            int bt = m >> 11, s0 = m & 2047;
            #pragma unroll
            for (int bb = 0; bb < 4; ++bb) {
                int n = n0 + woffB + bb * 16 + l16;
                float bvv = bias[n];
                int h = n >> 6, d = n & 63;
                bf16x4 o;
                #pragma unroll
                for (int r = 0; r < 4; ++r)
                    o[r] = (__bf16)(acc[a][bb][r] + bvv);
                *(bf16x4*)&outp[((size_t)(bt * 16 + h) * 64 + d) * 2048 + s0] = o;
            }
        }
    }
}

// ---------------------------------------------------------------------------
// Attention R7: grid (8, 64); 4 waves/block, 64 q-rows per wave.
// Per 64-key tile: stage K[64][64] and Vt-slice[64][64] via glds into
// double-buffered swizzled LDS (block-shared); S^T = K Q^T (16x16x32);
// relu^2 packed IN-REGISTER as the A-operand of PV 16x16x16 MFMAs
// (P[q=l16][key=quad*4+r] == A[m=l16][k=quad*4+j]); ctx[q][d] accumulated
// fp32. No P LDS traffic at all.
// ---------------------------------------------------------------------------
__global__ __launch_bounds__(256, 2) void attn_kernel(
    const __bf16* __restrict__ Q, const __bf16* __restrict__ K,
    const __bf16* __restrict__ Vt, const float* __restrict__ mask,
    float* __restrict__ out)
{
    __shared__ __bf16 Ks[2][64 * 64];   // [key][d], XOR-swizzled chunks
    __shared__ __bf16 Vs[2][64 * 64];   // [d][key], XOR-swizzled chunks

    const int tid  = threadIdx.x;
    const int lane = tid & 63;
    const int wave = tid >> 6;
    const int quad = lane >> 4;
    const int l16  = lane & 15;
    const int bh   = blockIdx.y;
    const int b    = bh >> 4;
    const int h    = bh & 15;
    const int q0   = blockIdx.x * 256 + wave * 64;

    const __bf16* Qb = Q  + (size_t)bh * 2048 * 64;
    const __bf16* Kb = K  + (size_t)bh * 2048 * 64;
    const __bf16* Vb = Vt + (size_t)bh * 64 * 2048;
    const float*  mb = mask + b * 2048;

    // staging lane geometry (shared by K and V): 2 insts/wave each
    const int srow = (lane >> 3);            // row within 8-row block
    const int schk = (lane & 7);             // LDS chunk this lane fills

    // Q fragments (B operand for S^T): lane n=l16 -> q, k = 8 contiguous d.
    bf16x8 aq[4][2];
    #pragma unroll
    for (int qi = 0; qi < 4; ++qi)
        #pragma unroll
        for (int kcd = 0; kcd < 2; ++kcd)
            aq[qi][kcd] = *(const bf16x8*)(Qb +
                (size_t)(q0 + qi * 16 + l16) * 64 + kcd * 32 + quad * 8);

    f32x4 co[4][4] = {};   // ctx[q-tile][d-tile], rows=q, cols=d

    // ---- stage tile 0 into buffer 0 ----
    #pragma unroll
    for (int i = 0; i < 2; ++i) {
        int rb = wave * 16 + i * 8;
        int r  = rb + srow;
        int c  = schk ^ (r & 7);
        glds16(Kb + (size_t)r * 64 + c * 8, &Ks[0][rb * 64]);
        glds16(Vb + (size_t)r * 2048 + 0 + c * 8, &Vs[0][rb * 64]);
    }

    for (int t = 0; t < 32; ++t) {
        const int k0 = t * 64;
        const int kn = (k0 + 64) & 2047;          // wrap: last prefetch benign
        const int nb = (t + 1) & 1;
        // ---- stage next tile (4 glds/wave) ----
        #pragma unroll
        for (int i = 0; i < 2; ++i) {
            int rb = wave * 16 + i * 8;
            int r  = rb + srow;
            int c  = schk ^ (r & 7);
            glds16(Kb + (size_t)(kn + r) * 64 + c * 8, &Ks[nb][rb * 64]);
            glds16(Vb + (size_t)r * 2048 + kn + c * 8, &Vs[nb][rb * 64]);
        }
        WAITCNT_VM4();          // this tile's 4 glds (older) complete
        __syncthreads();        // all waves' staging of tile t visible

        const __bf16* Kt = &Ks[t & 1][0];
        const __bf16* Vtile = &Vs[t & 1][0];

        // ---- S^T + relu^2, packed per 16-key chunk into PV A-frags ----
        bf16x4 pf[4][4];                           // [ki][qi]
        #pragma unroll
        for (int ki = 0; ki < 4; ++ki) {
            f32x4 st[4] = {};
            #pragma unroll
            for (int kcd = 0; kcd < 2; ++kcd) {
                int key = ki * 16 + l16;
                bf16x8 ak = *(const bf16x8*)&Kt[key * 64 +
                    (((kcd * 4 + quad) ^ (key & 7)) * 8)];
                #pragma unroll
                for (int qi = 0; qi < 4; ++qi)
                    st[qi] = MFMA16(ak, aq[qi][kcd], st[qi]);
            }
            floatx4 mk = *(const floatx4*)&mb[k0 + ki * 16 + quad * 4];
            #pragma unroll
            for (int qi = 0; qi < 4; ++qi) {
                bf16x4 pv;
                #pragma unroll
                for (int r = 0; r < 4; ++r) {
                    float x = st[qi][r] * 0.125f + mk[r];
                    x = fmaxf(x, 0.0f);
                    pv[r] = (__bf16)(x * x);
                }
                pf[ki][qi] = pv;
            }
        }

        // ---- PV: ctx[q][d] += P V via 16x16x16 (A=pf in registers) ----
        #pragma unroll
        for (int ki = 0; ki < 4; ++ki) {
            bf16x4 vb[4];
            #pragma unroll
            for (int dt = 0; dt < 4; ++dt) {
                int d = dt * 16 + l16;
                int g = ki * 2 + (quad >> 1);       // global 8-elem chunk
                vb[dt] = *(const bf16x4*)&Vtile[d * 64 +
                    ((g ^ (d & 7)) * 8) + (quad & 1) * 4];
            }
            #pragma unroll
            for (int qi = 0; qi < 4; ++qi) {
                s16x4 pa = __builtin_bit_cast(s16x4, pf[ki][qi]);
                #pragma unroll
                for (int dt = 0; dt < 4; ++dt)
                    co[qi][dt] = MFMA16K16(pa,
                        __builtin_bit_cast(s16x4, vb[dt]), co[qi][dt]);
            }
        }
        __syncthreads();        // everyone done reading buf t before overwrite
    }

    // Epilogue: ctx row = q = qi*16+quad*4+r, col = d = dt*16+l16.
    #pragma unroll
    for (int qi = 0; qi < 4; ++qi)
        #pragma unroll
        for (int r = 0; r < 4; ++r) {
            int q = q0 + qi * 16 + quad * 4 + r;
            float* orow = &out[(((size_t)b * 2048 + q) * 16 + h) * 64];
            #pragma unroll
            for (int dt = 0; dt < 4; ++dt)
                orow[dt * 16 + l16] = co[qi][dt][r];
        }
}

// ---------------------------------------------------------------------------
extern "C" void kernel_launch(void* const* d_in, const int* in_sizes, int n_in,
                              void* d_out, int out_size, void* d_ws, size_t ws_size,
                              hipStream_t stream) {
    const float* hidden = (const float*)d_in[0];   // [4,2048,1024]
    const float* mask   = (const float*)d_in[1];   // [4,1,1,2048]
    const float* Wq     = (const float*)d_in[2];
    const float* bq     = (const float*)d_in[3];
    const float* Wk     = (const float*)d_in[4];
    const float* bk     = (const float*)d_in[5];
    const float* Wv     = (const float*)d_in[6];
    const float* bv     = (const float*)d_in[7];
    float* out = (float*)d_out;

    __bf16* qws = (__bf16*)d_ws;                       // [64][2048][64]
    __bf16* kws = qws + (size_t)64 * 2048 * 64;        // [64][2048][64]
    __bf16* vws = kws + (size_t)64 * 2048 * 64;        // [64][64][2048]
    __bf16* Xb  = vws + (size_t)64 * 2048 * 64;        // [8192][1024]
    __bf16* Wqb = Xb  + (size_t)8192 * 1024;
    __bf16* Wkb = Wqb + (size_t)1024 * 1024;
    __bf16* Wvb = Wkb + (size_t)1024 * 1024;

    dim3 blk(256);
    convert_kernel<<<dim3(5632), blk, 0, stream>>>(hidden, Wq, Wk, Wv,
                                                   Xb, Wqb, Wkb, Wvb);
    qkv_gemm_kernel<<<dim3(24, 64), blk, 0, stream>>>(Xb, Wqb, Wkb, Wvb,
                                                      bq, bk, bv, qws, kws, vws);
    attn_kernel<<<dim3(8, 64), blk, 0, stream>>>(qws, kws, vws, mask, out);
}